// Round 1
// baseline (1443.358 us; speedup 1.0000x reference)
//
#include <hip/hip_runtime.h>
#include <math.h>
#include <stddef.h>

#define N_NODES 16384
#define F_DIM   500
#define E_DIM   128
#define C_DIM   10
#define B_DIM   4096
#define MAXDEG  128

typedef __attribute__((ext_vector_type(8))) short short8;   // 8 bf16 = 4 VGPRs
typedef __attribute__((ext_vector_type(4))) float f32x4;    // MFMA C/D

__device__ inline unsigned short f2bf(float f) {
    union { float f; unsigned int u; } v; v.f = f;
    unsigned int u = v.u;
    u += 0x7FFFu + ((u >> 16) & 1u);        // RNE
    return (unsigned short)(u >> 16);
}
__device__ inline float bf2f(unsigned short u) {
    union { unsigned int u; float f; } v; v.u = (unsigned int)u << 16;
    return v.f;
}
__device__ inline short8 cvt8(float4 a, float4 b) {
    short8 v;
    v[0] = (short)f2bf(a.x); v[1] = (short)f2bf(a.y);
    v[2] = (short)f2bf(a.z); v[3] = (short)f2bf(a.w);
    v[4] = (short)f2bf(b.x); v[5] = (short)f2bf(b.y);
    v[6] = (short)f2bf(b.z); v[7] = (short)f2bf(b.w);
    return v;
}

// ---------------------------------------------------------------------------
// K1 fused (block-ranged):
//  [0,64):    W2ab16[n][k] = bf16(W2[n][k])
//  [64,128):  W2bb16[n][k] = bf16(W2[n][128+k])
//  [128,144): Wl1t[k][e] = Wl1[e][k]   (fp32 transpose, 32x32 tiles)
//  [144,656): GEMM1 (LDS-free): Xb16[32-row tile][256] = bf16(data) @ bf16(W1)^T
//             (B fragments converted from W1 fp32 in-register — no Wt1 dep)
//  [656, 656+16384): adj row scan -> CSR (nbr ushort, deg int)
// ---------------------------------------------------------------------------
__global__ __launch_bounds__(256) void k_fuse1(const float* __restrict__ data,
                                               const float* __restrict__ W1,
                                               const float* __restrict__ W2,
                                               const float* __restrict__ Wl1,
                                               const float* __restrict__ adj,
                                               unsigned short* __restrict__ Xb16,
                                               unsigned short* __restrict__ nbr,
                                               int* __restrict__ deg,
                                               unsigned short* __restrict__ W2ab16,
                                               unsigned short* __restrict__ W2bb16,
                                               float* __restrict__ Wl1t) {
    __shared__ alignas(16) unsigned char smem[4352];
    const int bb = blockIdx.x;
    const int tid = threadIdx.x;

    if (bb < 64) {                                 // W2 self-half -> bf16
        int idx = bb * 256 + tid;                  // 128*128
        int n = idx >> 7, k = idx & 127;
        W2ab16[idx] = f2bf(W2[(size_t)n * 256 + k]);
        return;
    } else if (bb < 128) {                         // W2 neigh-half -> bf16
        int idx = (bb - 64) * 256 + tid;
        int n = idx >> 7, k = idx & 127;
        W2bb16[idx] = f2bf(W2[(size_t)n * 256 + 128 + k]);
        return;
    } else if (bb < 144) {                         // Wl1 transpose (fp32)
        float (*tile)[33] = (float (*)[33])smem;
        int tb = bb - 128;                         // 16 tiles (4x4)
        int k0 = (tb & 3) * 32, e0 = (tb >> 2) * 32;
        int tx = tid & 31, ty0 = tid >> 5;
#pragma unroll
        for (int q = 0; q < 4; ++q) {
            int ty = ty0 + q * 8;
            tile[ty][tx] = Wl1[(size_t)(e0 + ty) * 128 + k0 + tx];
        }
        __syncthreads();
#pragma unroll
        for (int q = 0; q < 4; ++q) {
            int ty = ty0 + q * 8;
            Wl1t[(size_t)(k0 + ty) * 128 + e0 + tx] = tile[tx][ty];
        }
        return;
    } else if (bb < 656) {
        // ---------------- GEMM1 (no LDS, no barriers) ----------------
        const int g = bb - 144;
        const int blockM = g * 32;
        const int w    = tid >> 6;          // wave: output cols w*64..w*64+63
        const int lane = tid & 63;
        const int l16  = lane & 15;
        const int quad = lane >> 4;
        f32x4 acc[2][4] = {};
#pragma unroll 2
        for (int c = 0; c < 16; ++c) {      // K = 512 (500 + zero pad)
            const int kq = (c << 5) + quad * 8;
            const bool ok0 = (kq + 4 <= F_DIM);
            const bool ok1 = (kq + 8 <= F_DIM);
            short8 af[2], bfr[4];
#pragma unroll
            for (int mt = 0; mt < 2; ++mt) {
                const float* ap = data + (size_t)(blockM + mt * 16 + l16) * F_DIM + kq;
                float4 f0 = ok0 ? *(const float4*)ap       : make_float4(0.f, 0.f, 0.f, 0.f);
                float4 f1 = ok1 ? *(const float4*)(ap + 4) : make_float4(0.f, 0.f, 0.f, 0.f);
                af[mt] = cvt8(f0, f1);
            }
#pragma unroll
            for (int nt = 0; nt < 4; ++nt) {
                int n = w * 64 + nt * 16 + l16;
                const float* bp = W1 + (size_t)(n & 127) * 1000 + (n >> 7) * F_DIM + kq;
                float4 g0 = ok0 ? *(const float4*)bp       : make_float4(0.f, 0.f, 0.f, 0.f);
                float4 g1 = ok1 ? *(const float4*)(bp + 4) : make_float4(0.f, 0.f, 0.f, 0.f);
                bfr[nt] = cvt8(g0, g1);
            }
#pragma unroll
            for (int mt = 0; mt < 2; ++mt)
#pragma unroll
                for (int nt = 0; nt < 4; ++nt)
                    acc[mt][nt] = __builtin_amdgcn_mfma_f32_16x16x32_bf16(af[mt], bfr[nt], acc[mt][nt], 0, 0, 0);
        }
        // C/D layout: col = lane&15, row = quad*4 + reg
#pragma unroll
        for (int mt = 0; mt < 2; ++mt)
#pragma unroll
            for (int nt = 0; nt < 4; ++nt) {
                int col = w * 64 + nt * 16 + l16;
#pragma unroll
                for (int r = 0; r < 4; ++r) {
                    int row = blockM + mt * 16 + quad * 4 + r;
                    Xb16[(size_t)row * 256 + col] = f2bf(acc[mt][nt][r]);
                }
            }
    } else {
        // ---------------- adj scan -> CSR ----------------
        const int i = bb - 656;
        int* s_cnt = (int*)smem;
        int* s_idx = ((int*)smem) + 4;          // 16 B offset
        const float4* row4 = (const float4*)(adj + (size_t)i * N_NODES);
        if (tid == 0) *s_cnt = 0;
        __syncthreads();
        float4 v[16];
#pragma unroll
        for (int p = 0; p < 16; ++p) v[p] = row4[p * 256 + tid];
#pragma unroll
        for (int p = 0; p < 16; ++p) {
            int col = p * 1024 + tid * 4;
            if (v[p].x != 0.f) { int q = atomicAdd(s_cnt, 1); if (q < MAXDEG) s_idx[q] = col;     }
            if (v[p].y != 0.f) { int q = atomicAdd(s_cnt, 1); if (q < MAXDEG) s_idx[q] = col + 1; }
            if (v[p].z != 0.f) { int q = atomicAdd(s_cnt, 1); if (q < MAXDEG) s_idx[q] = col + 2; }
            if (v[p].w != 0.f) { int q = atomicAdd(s_cnt, 1); if (q < MAXDEG) s_idx[q] = col + 3; }
        }
        __syncthreads();
        int cnt = *s_cnt; if (cnt > MAXDEG) cnt = MAXDEG;   // deg>=1 (self-loop)
        if (tid < cnt) nbr[(size_t)i * MAXDEG + tid] = (unsigned short)s_idx[tid];
        if (tid == 0) deg[i] = cnt;
    }
}

// ---------------------------------------------------------------------------
// K2: layer-1 gather + relu + l2norm. ONE WAVE PER NODE (no LDS, no barriers).
// Neighbor ids held in regs (2 per lane covers MAXDEG=128), __shfl broadcast.
// Half-wave parity split: lanes 0-31 even k, lanes 32-63 odd k; 32-lane
// ushort4 reads = one 256B coalesced row per iter.
// ---------------------------------------------------------------------------
__global__ __launch_bounds__(256) void k_gather(const unsigned short* __restrict__ nbr,
                                                const int* __restrict__ deg,
                                                const unsigned short* __restrict__ Xb16,
                                                const float* __restrict__ b1,
                                                unsigned short* __restrict__ H1b) {
    const int lane = threadIdx.x & 63;
    const int i = blockIdx.x * 4 + (threadIdx.x >> 6);
    const int cnt = deg[i];
    const int myn  = (lane < cnt)      ? (int)nbr[(size_t)i * MAXDEG + lane]      : 0;
    const int myn2 = (lane + 64 < cnt) ? (int)nbr[(size_t)i * MAXDEG + lane + 64] : 0;
    const int half = lane >> 5, l32 = lane & 31;
    float ax = 0.f, ay = 0.f, az = 0.f, aw = 0.f;
    for (int k = half; k < cnt; k += 2) {
        int kk = k & 63;
        int j1 = __shfl(myn, kk);
        int j2 = __shfl(myn2, kk);
        int j = (k < 64) ? j1 : j2;
        ushort4 x4 = *(const ushort4*)(Xb16 + (size_t)j * 256 + 128 + l32 * 4);
        ax += bf2f(x4.x); ay += bf2f(x4.y); az += bf2f(x4.z); aw += bf2f(x4.w);
    }
    ax += __shfl_xor(ax, 32); ay += __shfl_xor(ay, 32);
    az += __shfl_xor(az, 32); aw += __shfl_xor(aw, 32);
    ushort4 sx = *(const ushort4*)(Xb16 + (size_t)i * 256 + l32 * 4);
    float4 bb = *(const float4*)(b1 + l32 * 4);
    float fc = (float)cnt;
    float v0 = fmaxf(bf2f(sx.x) + ax / fc + bb.x, 0.f);
    float v1 = fmaxf(bf2f(sx.y) + ay / fc + bb.y, 0.f);
    float v2 = fmaxf(bf2f(sx.z) + az / fc + bb.z, 0.f);
    float v3 = fmaxf(bf2f(sx.w) + aw / fc + bb.w, 0.f);
    float s = v0 * v0 + v1 * v1 + v2 * v2 + v3 * v3;
#pragma unroll
    for (int off = 16; off > 0; off >>= 1) s += __shfl_xor(s, off);
    float rden = 1.0f / fmaxf(sqrtf(s), 1e-12f);
    if (half == 0) {
        ushort4 o;
        o.x = f2bf(v0 * rden); o.y = f2bf(v1 * rden);
        o.z = f2bf(v2 * rden); o.w = f2bf(v3 * rden);
        *(ushort4*)(H1b + (size_t)i * 128 + l32 * 4) = o;
    }
}

// ---------------------------------------------------------------------------
// K3: GEMM2 — no LDS, no barriers. B (128x128 bf16, 32KB) is L2-resident;
// fragments loaded straight from global. A rows gathered via nodes[] (selfp).
//  [0,512):   Yb16 = bf16(H1b @ W2b^T)   for all nodes
//  [512,640): Ya   = H1b[nodes] @ W2a^T  (fp32) for batch rows
// ---------------------------------------------------------------------------
__global__ __launch_bounds__(256) void k_gemm2(const unsigned short* __restrict__ H1b,
                                               const unsigned short* __restrict__ W2bb16,
                                               const unsigned short* __restrict__ W2ab16,
                                               const int* __restrict__ nodes,
                                               unsigned short* __restrict__ Yb16,
                                               float* __restrict__ Ya) {
    const int bb = blockIdx.x;
    const bool selfp = (bb >= 512);
    const unsigned short* B = selfp ? W2ab16 : W2bb16;
    const int blockM = (selfp ? (bb - 512) : bb) * 32;
    const int tid  = threadIdx.x;
    const int w    = tid >> 6;
    const int lane = tid & 63;
    const int l16  = lane & 15;
    const int quad = lane >> 4;
    int rsrc0 = blockM + l16,      rsrc1 = blockM + 16 + l16;
    if (selfp) { rsrc0 = nodes[rsrc0]; rsrc1 = nodes[rsrc1]; }
    short8 af[2][4], bfr[2][4];
#pragma unroll
    for (int c = 0; c < 4; ++c) {
        af[0][c] = *(const short8*)(H1b + (size_t)rsrc0 * 128 + c * 32 + quad * 8);
        af[1][c] = *(const short8*)(H1b + (size_t)rsrc1 * 128 + c * 32 + quad * 8);
    }
#pragma unroll
    for (int nt = 0; nt < 2; ++nt) {
        int n = w * 32 + nt * 16 + l16;
#pragma unroll
        for (int c = 0; c < 4; ++c)
            bfr[nt][c] = *(const short8*)(B + (size_t)n * 128 + c * 32 + quad * 8);
    }
    f32x4 acc[2][2] = {};
#pragma unroll
    for (int c = 0; c < 4; ++c)
#pragma unroll
        for (int mt = 0; mt < 2; ++mt)
#pragma unroll
            for (int nt = 0; nt < 2; ++nt)
                acc[mt][nt] = __builtin_amdgcn_mfma_f32_16x16x32_bf16(af[mt][c], bfr[nt][c], acc[mt][nt], 0, 0, 0);
#pragma unroll
    for (int mt = 0; mt < 2; ++mt)
#pragma unroll
        for (int nt = 0; nt < 2; ++nt) {
            int col = w * 32 + nt * 16 + l16;
#pragma unroll
            for (int r = 0; r < 4; ++r) {
                int row = blockM + mt * 16 + quad * 4 + r;
                if (selfp) Ya[(size_t)row * 128 + col] = acc[mt][nt][r];
                else       Yb16[(size_t)row * 128 + col] = f2bf(acc[mt][nt][r]);
            }
        }
}

// ---------------------------------------------------------------------------
// K4: layer-2 epilogue + classifier + softmax. ONE WAVE PER BATCH NODE.
// Gather (parity halves) -> l2norm -> Lin matvec (2 cols/lane, Wl1t float2
// coalesced, h broadcast via shfl) -> head via 64-lane tree reduce -> softmax.
// No LDS, no barriers; every phase uses all 64 lanes.
// ---------------------------------------------------------------------------
__global__ __launch_bounds__(256) void k_l2head(const int* __restrict__ nodes,
                                                const unsigned short* __restrict__ nbr,
                                                const int* __restrict__ deg,
                                                const unsigned short* __restrict__ Yb16,
                                                const float* __restrict__ Ya,
                                                const float* __restrict__ b2,
                                                const float* __restrict__ Wl1t,
                                                const float* __restrict__ bl1,
                                                const float* __restrict__ Wl2,
                                                const float* __restrict__ bl2,
                                                float* __restrict__ out) {
    const int lane = threadIdx.x & 63;
    const int b = blockIdx.x * 4 + (threadIdx.x >> 6);
    const int n = nodes[b];
    const int cnt = deg[n];
    const int myn  = (lane < cnt)      ? (int)nbr[(size_t)n * MAXDEG + lane]      : 0;
    const int myn2 = (lane + 64 < cnt) ? (int)nbr[(size_t)n * MAXDEG + lane + 64] : 0;
    const int half = lane >> 5, l32 = lane & 31;
    float ax = 0.f, ay = 0.f, az = 0.f, aw = 0.f;
    for (int k = half; k < cnt; k += 2) {
        int kk = k & 63;
        int j1 = __shfl(myn, kk);
        int j2 = __shfl(myn2, kk);
        int j = (k < 64) ? j1 : j2;
        ushort4 y4 = *(const ushort4*)(Yb16 + (size_t)j * 128 + l32 * 4);
        ax += bf2f(y4.x); ay += bf2f(y4.y); az += bf2f(y4.z); aw += bf2f(y4.w);
    }
    ax += __shfl_xor(ax, 32); ay += __shfl_xor(ay, 32);
    az += __shfl_xor(az, 32); aw += __shfl_xor(aw, 32);
    float4 ya = *(const float4*)(Ya + (size_t)b * 128 + l32 * 4);
    float4 bb = *(const float4*)(b2 + l32 * 4);
    float fc = (float)cnt;
    float h0 = fmaxf(ya.x + ax / fc + bb.x, 0.f);
    float h1 = fmaxf(ya.y + ay / fc + bb.y, 0.f);
    float h2 = fmaxf(ya.z + az / fc + bb.z, 0.f);
    float h3 = fmaxf(ya.w + aw / fc + bb.w, 0.f);
    float s = h0 * h0 + h1 * h1 + h2 * h2 + h3 * h3;
#pragma unroll
    for (int off = 16; off > 0; off >>= 1) s += __shfl_xor(s, off);
    float rden = 1.0f / fmaxf(sqrtf(s), 1e-12f);
    h0 *= rden; h1 *= rden; h2 *= rden; h3 *= rden;
    // Lin: x[e] for e = 2*lane, 2*lane+1 (covers 128 cols across the wave)
    float2 bl = *(const float2*)(bl1 + 2 * lane);
    float x0 = bl.x, x1 = bl.y;
    const float* wl = Wl1t + 2 * lane;
    for (int m = 0; m < 32; ++m) {
        float k0 = __shfl(h0, m), k1 = __shfl(h1, m), k2 = __shfl(h2, m), k3 = __shfl(h3, m);
        float2 w0 = *(const float2*)(wl + (size_t)(m * 4 + 0) * 128);
        float2 w1 = *(const float2*)(wl + (size_t)(m * 4 + 1) * 128);
        float2 w2 = *(const float2*)(wl + (size_t)(m * 4 + 2) * 128);
        float2 w3 = *(const float2*)(wl + (size_t)(m * 4 + 3) * 128);
        x0 += k0 * w0.x + k1 * w1.x + k2 * w2.x + k3 * w3.x;
        x1 += k0 * w0.y + k1 * w1.y + k2 * w2.y + k3 * w3.y;
    }
    // head: 10 outputs, each a 64-lane tree reduce of 2-elem partials
    float cv[C_DIM];
#pragma unroll
    for (int cc = 0; cc < C_DIM; ++cc) {
        float2 w = *(const float2*)(Wl2 + (size_t)cc * 128 + 2 * lane);
        float p = x0 * w.x + x1 * w.y;
#pragma unroll
        for (int off = 32; off > 0; off >>= 1) p += __shfl_xor(p, off);
        cv[cc] = p + bl2[cc];
    }
    float mx = cv[0];
#pragma unroll
    for (int cc = 1; cc < C_DIM; ++cc) mx = fmaxf(mx, cv[cc]);
    float se = 0.f;
#pragma unroll
    for (int cc = 0; cc < C_DIM; ++cc) { cv[cc] = expf(cv[cc] - mx); se += cv[cc]; }
    float rse = 1.0f / se;
    float o = cv[0];
#pragma unroll
    for (int cc = 1; cc < C_DIM; ++cc) o = (lane == cc) ? cv[cc] : o;
    if (lane < C_DIM) out[(size_t)b * C_DIM + lane] = o * rse;
}

// ---------------------------------------------------------------------------
// Launch
// ---------------------------------------------------------------------------
extern "C" void kernel_launch(void* const* d_in, const int* in_sizes, int n_in,
                              void* d_out, int out_size, void* d_ws, size_t ws_size,
                              hipStream_t stream) {
    const int*   nodes = (const int*)  d_in[0];
    const float* adj   = (const float*)d_in[1];
    const float* data  = (const float*)d_in[2];
    const float* W1    = (const float*)d_in[3];
    const float* b1    = (const float*)d_in[4];
    const float* W2    = (const float*)d_in[5];
    const float* b2    = (const float*)d_in[6];
    const float* Wl1   = (const float*)d_in[7];
    const float* bl1   = (const float*)d_in[8];
    const float* Wl2   = (const float*)d_in[9];
    const float* bl2   = (const float*)d_in[10];
    float* out = (float*)d_out;

    // workspace: fp32 first, then bf16/ushort, then int (16B aligned)
    float* Wl1t = (float*)d_ws;                              // 128*128
    float* Ya   = Wl1t + 16384;                              // 4096*128
    unsigned short* W2ab16 = (unsigned short*)(Ya + (size_t)B_DIM * 128); // 128*128
    unsigned short* W2bb16 = W2ab16 + 16384;                 // 128*128
    unsigned short* Xb16   = W2bb16 + 16384;                 // 16384*256
    unsigned short* H1b    = Xb16 + (size_t)N_NODES * 256;   // 16384*128
    unsigned short* Yb16   = H1b + (size_t)N_NODES * 128;    // 16384*128
    unsigned short* nbr    = Yb16 + (size_t)N_NODES * 128;   // 16384*128
    int* deg = (int*)(nbr + (size_t)N_NODES * MAXDEG);       // 16384

    // K1: prep + GEMM1 + adj scan fused (144 + 512 + 16384 blocks)
    k_fuse1<<<144 + 512 + N_NODES, 256, 0, stream>>>(data, W1, W2, Wl1, adj,
                                                     Xb16, nbr, deg,
                                                     W2ab16, W2bb16, Wl1t);
    // K2: wave-per-node layer-1 gather (16384 waves = 4096 blocks)
    k_gather<<<N_NODES / 4, 256, 0, stream>>>(nbr, deg, Xb16, b1, H1b);
    // K3: barrier-less GEMM2 (Yb all nodes + Ya batch rows)
    k_gemm2<<<512 + 128, 256, 0, stream>>>(H1b, W2bb16, W2ab16, nodes, Yb16, Ya);
    // K4: wave-per-batch-node layer-2 + head (4096 waves = 1024 blocks)
    k_l2head<<<B_DIM / 4, 256, 0, stream>>>(nodes, nbr, deg, Yb16, Ya, b2,
                                            Wl1t, bl1, Wl2, bl2, out);
}

// Round 2
// 1433.942 us; speedup vs baseline: 1.0066x; 1.0066x over previous
//
#include <hip/hip_runtime.h>
#include <math.h>
#include <stddef.h>

#define N_NODES 16384
#define F_DIM   500
#define E_DIM   128
#define C_DIM   10
#define B_DIM   4096
#define MAXDEG  128

typedef __attribute__((ext_vector_type(8))) short short8;   // 8 bf16 = 4 VGPRs
typedef __attribute__((ext_vector_type(4))) float f32x4;    // MFMA C/D

__device__ inline unsigned short f2bf(float f) {
    union { float f; unsigned int u; } v; v.f = f;
    unsigned int u = v.u;
    u += 0x7FFFu + ((u >> 16) & 1u);        // RNE
    return (unsigned short)(u >> 16);
}
__device__ inline float bf2f(unsigned short u) {
    union { unsigned int u; float f; } v; v.u = (unsigned int)u << 16;
    return v.f;
}
__device__ inline short8 cvt8(float4 a, float4 b) {
    short8 v;
    v[0] = (short)f2bf(a.x); v[1] = (short)f2bf(a.y);
    v[2] = (short)f2bf(a.z); v[3] = (short)f2bf(a.w);
    v[4] = (short)f2bf(b.x); v[5] = (short)f2bf(b.y);
    v[6] = (short)f2bf(b.z); v[7] = (short)f2bf(b.w);
    return v;
}

// ---------------------------------------------------------------------------
// KA (block-ranged, all small prep + GEMM1):
//  [0,64):    W2ab16[n][k] = bf16(W2[n][k])
//  [64,128):  W2bb16[n][k] = bf16(W2[n][128+k])
//  [128,144): Wl1t[k][e] = Wl1[e][k]   (fp32 transpose, 32x32 tiles)
//  [144,656): GEMM1 (LDS-free): Xb16[32-row tile][256] = bf16(data) @ bf16(W1)^T
// ---------------------------------------------------------------------------
__global__ __launch_bounds__(256) void k_prep1(const float* __restrict__ data,
                                               const float* __restrict__ W1,
                                               const float* __restrict__ W2,
                                               const float* __restrict__ Wl1,
                                               unsigned short* __restrict__ Xb16,
                                               unsigned short* __restrict__ W2ab16,
                                               unsigned short* __restrict__ W2bb16,
                                               float* __restrict__ Wl1t) {
    __shared__ float tile[32][33];
    const int bb = blockIdx.x;
    const int tid = threadIdx.x;

    if (bb < 64) {                                 // W2 self-half -> bf16
        int idx = bb * 256 + tid;                  // 128*128
        int n = idx >> 7, k = idx & 127;
        W2ab16[idx] = f2bf(W2[(size_t)n * 256 + k]);
        return;
    } else if (bb < 128) {                         // W2 neigh-half -> bf16
        int idx = (bb - 64) * 256 + tid;
        int n = idx >> 7, k = idx & 127;
        W2bb16[idx] = f2bf(W2[(size_t)n * 256 + 128 + k]);
        return;
    } else if (bb < 144) {                         // Wl1 transpose (fp32)
        int tb = bb - 128;                         // 16 tiles (4x4)
        int k0 = (tb & 3) * 32, e0 = (tb >> 2) * 32;
        int tx = tid & 31, ty0 = tid >> 5;
#pragma unroll
        for (int q = 0; q < 4; ++q) {
            int ty = ty0 + q * 8;
            tile[ty][tx] = Wl1[(size_t)(e0 + ty) * 128 + k0 + tx];
        }
        __syncthreads();
#pragma unroll
        for (int q = 0; q < 4; ++q) {
            int ty = ty0 + q * 8;
            Wl1t[(size_t)(k0 + ty) * 128 + e0 + tx] = tile[tx][ty];
        }
        return;
    }
    // ---------------- GEMM1 (no LDS, no barriers) ----------------
    const int g = bb - 144;
    const int blockM = g * 32;
    const int w    = tid >> 6;              // wave: output cols w*64..w*64+63
    const int lane = tid & 63;
    const int l16  = lane & 15;
    const int quad = lane >> 4;
    f32x4 acc[2][4] = {};
#pragma unroll 2
    for (int c = 0; c < 16; ++c) {          // K = 512 (500 + zero pad)
        const int kq = (c << 5) + quad * 8;
        const bool ok0 = (kq + 4 <= F_DIM);
        const bool ok1 = (kq + 8 <= F_DIM);
        short8 af[2], bfr[4];
#pragma unroll
        for (int mt = 0; mt < 2; ++mt) {
            const float* ap = data + (size_t)(blockM + mt * 16 + l16) * F_DIM + kq;
            float4 f0 = ok0 ? *(const float4*)ap       : make_float4(0.f, 0.f, 0.f, 0.f);
            float4 f1 = ok1 ? *(const float4*)(ap + 4) : make_float4(0.f, 0.f, 0.f, 0.f);
            af[mt] = cvt8(f0, f1);
        }
#pragma unroll
        for (int nt = 0; nt < 4; ++nt) {
            int n = w * 64 + nt * 16 + l16;
            const float* bp = W1 + (size_t)(n & 127) * 1000 + (n >> 7) * F_DIM + kq;
            float4 g0 = ok0 ? *(const float4*)bp       : make_float4(0.f, 0.f, 0.f, 0.f);
            float4 g1 = ok1 ? *(const float4*)(bp + 4) : make_float4(0.f, 0.f, 0.f, 0.f);
            bfr[nt] = cvt8(g0, g1);
        }
#pragma unroll
        for (int mt = 0; mt < 2; ++mt)
#pragma unroll
            for (int nt = 0; nt < 4; ++nt)
                acc[mt][nt] = __builtin_amdgcn_mfma_f32_16x16x32_bf16(af[mt], bfr[nt], acc[mt][nt], 0, 0, 0);
    }
    // C/D layout: col = lane&15, row = quad*4 + reg
#pragma unroll
    for (int mt = 0; mt < 2; ++mt)
#pragma unroll
        for (int nt = 0; nt < 4; ++nt) {
            int col = w * 64 + nt * 16 + l16;
#pragma unroll
            for (int r = 0; r < 4; ++r) {
                int row = blockM + mt * 16 + quad * 4 + r;
                Xb16[(size_t)row * 256 + col] = f2bf(acc[mt][nt][r]);
            }
        }
}

// ---------------------------------------------------------------------------
// KB: fused adj-scan + layer-1 gather + relu + l2norm. One block per node.
// Scan the 64KB adj row into s_idx (LDS CSR), write nbr/deg for reuse, then
// immediately gather Xb16 neighbor halves (L2/L3-resident) and normalize.
// The gather's cache-read latency hides under the grid's HBM-bound scan.
// ---------------------------------------------------------------------------
__global__ __launch_bounds__(256) void k_scan_gather(const float* __restrict__ adj,
                                                     const unsigned short* __restrict__ Xb16,
                                                     const float* __restrict__ b1,
                                                     unsigned short* __restrict__ nbr,
                                                     int* __restrict__ deg,
                                                     unsigned short* __restrict__ H1b) {
    const int i = blockIdx.x;
    const int tid = threadIdx.x;
    __shared__ int s_cnt;
    __shared__ int s_idx[MAXDEG];
    __shared__ float s_part[8][128];
    __shared__ float s_w[2];

    // ---- scan phase ----
    const float4* row4 = (const float4*)(adj + (size_t)i * N_NODES);
    if (tid == 0) s_cnt = 0;
    __syncthreads();
    float4 v[16];
#pragma unroll
    for (int p = 0; p < 16; ++p) v[p] = row4[p * 256 + tid];
#pragma unroll
    for (int p = 0; p < 16; ++p) {
        int col = p * 1024 + tid * 4;
        if (v[p].x != 0.f) { int q = atomicAdd(&s_cnt, 1); if (q < MAXDEG) s_idx[q] = col;     }
        if (v[p].y != 0.f) { int q = atomicAdd(&s_cnt, 1); if (q < MAXDEG) s_idx[q] = col + 1; }
        if (v[p].z != 0.f) { int q = atomicAdd(&s_cnt, 1); if (q < MAXDEG) s_idx[q] = col + 2; }
        if (v[p].w != 0.f) { int q = atomicAdd(&s_cnt, 1); if (q < MAXDEG) s_idx[q] = col + 3; }
    }
    __syncthreads();
    int cnt = s_cnt; if (cnt > MAXDEG) cnt = MAXDEG;        // deg>=1 (self-loop)
    if (tid < cnt) nbr[(size_t)i * MAXDEG + tid] = (unsigned short)s_idx[tid];
    if (tid == 0) deg[i] = cnt;

    // ---- gather phase (8 groups x 32 lanes) ----
    const int g = tid >> 5, l = tid & 31;
    float4 a4 = make_float4(0.f, 0.f, 0.f, 0.f);
    for (int k = g; k < cnt; k += 8) {
        ushort4 x4 = ((const ushort4*)(Xb16 + (size_t)s_idx[k] * 256 + 128))[l];
        a4.x += bf2f(x4.x); a4.y += bf2f(x4.y); a4.z += bf2f(x4.z); a4.w += bf2f(x4.w);
    }
    *(float4*)&s_part[g][l * 4] = a4;
    __syncthreads();
    float vv = 0.f;
    if (tid < 128) {
        float tot = 0.f;
#pragma unroll
        for (int g2 = 0; g2 < 8; ++g2) tot += s_part[g2][tid];
        vv = bf2f(Xb16[(size_t)i * 256 + tid]) + tot / (float)cnt + b1[tid];
        vv = fmaxf(vv, 0.f);
        float s = vv * vv;
#pragma unroll
        for (int off = 32; off > 0; off >>= 1) s += __shfl_down(s, off, 64);
        if ((tid & 63) == 0) s_w[tid >> 6] = s;
    }
    __syncthreads();
    if (tid < 128) {
        float denom = fmaxf(sqrtf(s_w[0] + s_w[1]), 1e-12f);
        H1b[(size_t)i * 128 + tid] = f2bf(vv / denom);
    }
}

// ---------------------------------------------------------------------------
// KC: GEMM2 — no LDS, no barriers. B (128x128 bf16, 32KB) is L2-resident.
//  [0,512):   Yb16 = bf16(H1b @ W2b^T)   for all nodes
//  [512,640): Ya   = H1b[nodes] @ W2a^T  (fp32) for batch rows
// ---------------------------------------------------------------------------
__global__ __launch_bounds__(256) void k_gemm2(const unsigned short* __restrict__ H1b,
                                               const unsigned short* __restrict__ W2bb16,
                                               const unsigned short* __restrict__ W2ab16,
                                               const int* __restrict__ nodes,
                                               unsigned short* __restrict__ Yb16,
                                               float* __restrict__ Ya) {
    const int bb = blockIdx.x;
    const bool selfp = (bb >= 512);
    const unsigned short* B = selfp ? W2ab16 : W2bb16;
    const int blockM = (selfp ? (bb - 512) : bb) * 32;
    const int tid  = threadIdx.x;
    const int w    = tid >> 6;
    const int lane = tid & 63;
    const int l16  = lane & 15;
    const int quad = lane >> 4;
    int rsrc0 = blockM + l16,      rsrc1 = blockM + 16 + l16;
    if (selfp) { rsrc0 = nodes[rsrc0]; rsrc1 = nodes[rsrc1]; }
    short8 af[2][4], bfr[2][4];
#pragma unroll
    for (int c = 0; c < 4; ++c) {
        af[0][c] = *(const short8*)(H1b + (size_t)rsrc0 * 128 + c * 32 + quad * 8);
        af[1][c] = *(const short8*)(H1b + (size_t)rsrc1 * 128 + c * 32 + quad * 8);
    }
#pragma unroll
    for (int nt = 0; nt < 2; ++nt) {
        int n = w * 32 + nt * 16 + l16;
#pragma unroll
        for (int c = 0; c < 4; ++c)
            bfr[nt][c] = *(const short8*)(B + (size_t)n * 128 + c * 32 + quad * 8);
    }
    f32x4 acc[2][2] = {};
#pragma unroll
    for (int c = 0; c < 4; ++c)
#pragma unroll
        for (int mt = 0; mt < 2; ++mt)
#pragma unroll
            for (int nt = 0; nt < 2; ++nt)
                acc[mt][nt] = __builtin_amdgcn_mfma_f32_16x16x32_bf16(af[mt][c], bfr[nt][c], acc[mt][nt], 0, 0, 0);
#pragma unroll
    for (int mt = 0; mt < 2; ++mt)
#pragma unroll
        for (int nt = 0; nt < 2; ++nt) {
            int col = w * 32 + nt * 16 + l16;
#pragma unroll
            for (int r = 0; r < 4; ++r) {
                int row = blockM + mt * 16 + quad * 4 + r;
                if (selfp) Ya[(size_t)row * 128 + col] = acc[mt][nt][r];
                else       Yb16[(size_t)row * 128 + col] = f2bf(acc[mt][nt][r]);
            }
        }
}

// ---------------------------------------------------------------------------
// KD: layer-2 epilogue + classifier + softmax. ONE WAVE PER BATCH NODE.
// Gather (parity halves) -> l2norm -> Lin matvec (2 cols/lane, Wl1t float2
// coalesced, h broadcast via shfl) -> head via 64-lane tree reduce -> softmax.
// ---------------------------------------------------------------------------
__global__ __launch_bounds__(256) void k_l2head(const int* __restrict__ nodes,
                                                const unsigned short* __restrict__ nbr,
                                                const int* __restrict__ deg,
                                                const unsigned short* __restrict__ Yb16,
                                                const float* __restrict__ Ya,
                                                const float* __restrict__ b2,
                                                const float* __restrict__ Wl1t,
                                                const float* __restrict__ bl1,
                                                const float* __restrict__ Wl2,
                                                const float* __restrict__ bl2,
                                                float* __restrict__ out) {
    const int lane = threadIdx.x & 63;
    const int b = blockIdx.x * 4 + (threadIdx.x >> 6);
    const int n = nodes[b];
    const int cnt = deg[n];
    const int myn  = (lane < cnt)      ? (int)nbr[(size_t)n * MAXDEG + lane]      : 0;
    const int myn2 = (lane + 64 < cnt) ? (int)nbr[(size_t)n * MAXDEG + lane + 64] : 0;
    const int half = lane >> 5, l32 = lane & 31;
    float ax = 0.f, ay = 0.f, az = 0.f, aw = 0.f;
    for (int k = half; k < cnt; k += 2) {
        int kk = k & 63;
        int j1 = __shfl(myn, kk);
        int j2 = __shfl(myn2, kk);
        int j = (k < 64) ? j1 : j2;
        ushort4 y4 = *(const ushort4*)(Yb16 + (size_t)j * 128 + l32 * 4);
        ax += bf2f(y4.x); ay += bf2f(y4.y); az += bf2f(y4.z); aw += bf2f(y4.w);
    }
    ax += __shfl_xor(ax, 32); ay += __shfl_xor(ay, 32);
    az += __shfl_xor(az, 32); aw += __shfl_xor(aw, 32);
    float4 ya = *(const float4*)(Ya + (size_t)b * 128 + l32 * 4);
    float4 bb = *(const float4*)(b2 + l32 * 4);
    float fc = (float)cnt;
    float h0 = fmaxf(ya.x + ax / fc + bb.x, 0.f);
    float h1 = fmaxf(ya.y + ay / fc + bb.y, 0.f);
    float h2 = fmaxf(ya.z + az / fc + bb.z, 0.f);
    float h3 = fmaxf(ya.w + aw / fc + bb.w, 0.f);
    float s = h0 * h0 + h1 * h1 + h2 * h2 + h3 * h3;
#pragma unroll
    for (int off = 16; off > 0; off >>= 1) s += __shfl_xor(s, off);
    float rden = 1.0f / fmaxf(sqrtf(s), 1e-12f);
    h0 *= rden; h1 *= rden; h2 *= rden; h3 *= rden;
    // Lin: x[e] for e = 2*lane, 2*lane+1 (covers 128 cols across the wave)
    float2 bl = *(const float2*)(bl1 + 2 * lane);
    float x0 = bl.x, x1 = bl.y;
    const float* wl = Wl1t + 2 * lane;
    for (int m = 0; m < 32; ++m) {
        float k0 = __shfl(h0, m), k1 = __shfl(h1, m), k2 = __shfl(h2, m), k3 = __shfl(h3, m);
        float2 w0 = *(const float2*)(wl + (size_t)(m * 4 + 0) * 128);
        float2 w1 = *(const float2*)(wl + (size_t)(m * 4 + 1) * 128);
        float2 w2 = *(const float2*)(wl + (size_t)(m * 4 + 2) * 128);
        float2 w3 = *(const float2*)(wl + (size_t)(m * 4 + 3) * 128);
        x0 += k0 * w0.x + k1 * w1.x + k2 * w2.x + k3 * w3.x;
        x1 += k0 * w0.y + k1 * w1.y + k2 * w2.y + k3 * w3.y;
    }
    // head: 10 outputs, each a 64-lane tree reduce of 2-elem partials
    float cv[C_DIM];
#pragma unroll
    for (int cc = 0; cc < C_DIM; ++cc) {
        float2 w = *(const float2*)(Wl2 + (size_t)cc * 128 + 2 * lane);
        float p = x0 * w.x + x1 * w.y;
#pragma unroll
        for (int off = 32; off > 0; off >>= 1) p += __shfl_xor(p, off);
        cv[cc] = p + bl2[cc];
    }
    float mx = cv[0];
#pragma unroll
    for (int cc = 1; cc < C_DIM; ++cc) mx = fmaxf(mx, cv[cc]);
    float se = 0.f;
#pragma unroll
    for (int cc = 0; cc < C_DIM; ++cc) { cv[cc] = expf(cv[cc] - mx); se += cv[cc]; }
    float rse = 1.0f / se;
    float o = cv[0];
#pragma unroll
    for (int cc = 1; cc < C_DIM; ++cc) o = (lane == cc) ? cv[cc] : o;
    if (lane < C_DIM) out[(size_t)b * C_DIM + lane] = o * rse;
}

// ---------------------------------------------------------------------------
// Launch
// ---------------------------------------------------------------------------
extern "C" void kernel_launch(void* const* d_in, const int* in_sizes, int n_in,
                              void* d_out, int out_size, void* d_ws, size_t ws_size,
                              hipStream_t stream) {
    const int*   nodes = (const int*)  d_in[0];
    const float* adj   = (const float*)d_in[1];
    const float* data  = (const float*)d_in[2];
    const float* W1    = (const float*)d_in[3];
    const float* b1    = (const float*)d_in[4];
    const float* W2    = (const float*)d_in[5];
    const float* b2    = (const float*)d_in[6];
    const float* Wl1   = (const float*)d_in[7];
    const float* bl1   = (const float*)d_in[8];
    const float* Wl2   = (const float*)d_in[9];
    const float* bl2   = (const float*)d_in[10];
    float* out = (float*)d_out;

    // workspace: fp32 first, then bf16/ushort, then int (16B aligned)
    float* Wl1t = (float*)d_ws;                              // 128*128
    float* Ya   = Wl1t + 16384;                              // 4096*128
    unsigned short* W2ab16 = (unsigned short*)(Ya + (size_t)B_DIM * 128); // 128*128
    unsigned short* W2bb16 = W2ab16 + 16384;                 // 128*128
    unsigned short* Xb16   = W2bb16 + 16384;                 // 16384*256
    unsigned short* H1b    = Xb16 + (size_t)N_NODES * 256;   // 16384*128
    unsigned short* Yb16   = H1b + (size_t)N_NODES * 128;    // 16384*128
    unsigned short* nbr    = Yb16 + (size_t)N_NODES * 128;   // 16384*128
    int* deg = (int*)(nbr + (size_t)N_NODES * MAXDEG);       // 16384

    // KA: weight prep + GEMM1 (656 blocks, ~15 us)
    k_prep1<<<656, 256, 0, stream>>>(data, W1, W2, Wl1,
                                     Xb16, W2ab16, W2bb16, Wl1t);
    // KB: fused adj scan + layer-1 gather + norm (HBM-bound, ~200-280 us)
    k_scan_gather<<<N_NODES, 256, 0, stream>>>(adj, Xb16, b1, nbr, deg, H1b);
    // KC: barrier-less GEMM2 (Yb all nodes + Ya batch rows)
    k_gemm2<<<512 + 128, 256, 0, stream>>>(H1b, W2bb16, W2ab16, nodes, Yb16, Ya);
    // KD: wave-per-batch-node layer-2 + head (4096 waves = 1024 blocks)
    k_l2head<<<B_DIM / 4, 256, 0, stream>>>(nodes, nbr, deg, Yb16, Ya, b2,
                                            Wl1t, bl1, Wl2, bl2, out);
}